// Round 6
// baseline (249.316 us; speedup 1.0000x reference)
//
#include <hip/hip_runtime.h>
#include <hip/hip_bf16.h>
#include <stdint.h>
#include <stddef.h>

#define DIM 768

typedef short short8 __attribute__((ext_vector_type(8)));
typedef float f32x4 __attribute__((ext_vector_type(4)));

__device__ inline unsigned short f2bf_rne(float f) {
    union { float f; unsigned u; } x; x.f = f;
    unsigned r = x.u + 0x7fffu + ((x.u >> 16) & 1u);
    return (unsigned short)(r >> 16);
}

__device__ inline void gload_lds16(const void* g, void* l) {
    __builtin_amdgcn_global_load_lds((const __attribute__((address_space(1))) void*)g,
                                     (__attribute__((address_space(3))) void*)l, 16, 0, 0);
}

// Prep kernel, 1024 threads/block (unchanged from R5 — proven).
//  Blocks [0, ntok/16): wave-per-row gather + block-aggregated compaction.
//  Blocks [ntok/16, +144): W [K][N] fp32 -> Bt [N][K] bf16 via LDS transpose.
__global__ __launch_bounds__(1024) void prep_kernel(
    const int* __restrict__ token,
    const int* __restrict__ need_mapper,
    const float* __restrict__ emb,
    const float* __restrict__ w,
    float* __restrict__ out,
    unsigned short* __restrict__ Acmp,
    unsigned short* __restrict__ Bt,
    int* __restrict__ rowmap,
    int* __restrict__ cnt,
    int nGatherBlk)
{
    const int tid = threadIdx.x;
    if ((int)blockIdx.x < nGatherBlk) {
        __shared__ int sneed[16], soffs[16], sbase;
        const int wave = tid >> 6, lane = tid & 63;
        const int r = blockIdx.x * 16 + wave;
        const int tok = token[r];
        const int need = need_mapper[tok];
        if (lane == 0) sneed[wave] = need;

        const float* src = emb + (size_t)tok * DIM;
        float4 v[3];
#pragma unroll
        for (int j = 0; j < 3; ++j)
            v[j] = *(const float4*)(src + (j * 64 + lane) * 4);

        __syncthreads();
        if (tid == 0) {
            int tot = 0;
#pragma unroll
            for (int i = 0; i < 16; ++i) { soffs[i] = tot; tot += sneed[i]; }
            sbase = atomicAdd(cnt, tot);
        }
        __syncthreads();

        if (need) {
            const int pos = sbase + soffs[wave];
            if (lane == 0) rowmap[pos] = r;
            unsigned short* arow = Acmp + (size_t)pos * DIM;
#pragma unroll
            for (int j = 0; j < 3; ++j) {
                ushort4 h;
                h.x = f2bf_rne(v[j].x); h.y = f2bf_rne(v[j].y);
                h.z = f2bf_rne(v[j].z); h.w = f2bf_rne(v[j].w);
                *(ushort4*)(arow + (j * 64 + lane) * 4) = h;
            }
        } else {
            float* drow = out + (size_t)r * DIM;
#pragma unroll
            for (int j = 0; j < 3; ++j)
                *(float4*)(drow + (j * 64 + lane) * 4) = v[j];
        }
        return;
    }

    __shared__ unsigned short t[64][65];
    const int b = blockIdx.x - nGatherBlk;        // 0..143
    const int k0 = (b / 12) * 64, n0 = (b % 12) * 64;
#pragma unroll
    for (int p = 0; p < 4; ++p) {
        int e = p * 1024 + tid;
        int r = e >> 6, c = e & 63;
        t[c][r] = f2bf_rne(w[(size_t)(k0 + r) * DIM + n0 + c]);
    }
    __syncthreads();
#pragma unroll
    for (int p = 0; p < 4; ++p) {
        int e = p * 1024 + tid;
        int r = e >> 6, c = e & 63;
        Bt[(size_t)(n0 + r) * DIM + k0 + c] = t[r][c];
    }
}

// GEMM on compacted rows, 64m x 128n tiles (uniform ~3 blocks/CU at Mp~8192).
// BK=32, 4 waves in 2x2, wave tile 32m x 64n: 3 global_load_lds + 6 ds_read_b128
// + 8 MFMA (16x16x32 bf16) per wave per K-step. rowmap staged in LDS; scatter
// store to out; rows past Mp carry rmap=-1 and are skipped.
__global__ __launch_bounds__(256) void gemm_kernel(
    const unsigned short* __restrict__ A,    // [Mp][768] bf16, compacted
    const unsigned short* __restrict__ Bt,   // [768][768] bf16, n-major
    const float* __restrict__ bias,
    const int* __restrict__ rowmap,
    const int* __restrict__ cnt,
    float* __restrict__ out)
{
    const int Mp = *cnt;
    const int tile_n = blockIdx.x;   // 0..5
    const int tile_m = blockIdx.y;   // 0..255 (worst case)
    if (tile_m * 64 >= Mp) return;

    __shared__ unsigned short As[64 * 32];    // 4 KB
    __shared__ unsigned short Bs[128 * 32];   // 8 KB
    __shared__ int rmap[64];

    const int tid  = threadIdx.x;
    const int wave = tid >> 6;
    const int lane = tid & 63;
    const int quad = lane >> 4;
    const int l15  = lane & 15;
    const int wm   = wave >> 1;
    const int wn   = wave & 1;

    if (tid < 64) {
        int gm = tile_m * 64 + tid;
        rmap[tid] = (gm < Mp) ? rowmap[gm] : -1;
    }

    const unsigned short* Ag = A  + (size_t)(tile_m * 64 + (tid >> 2)) * DIM + (tid & 3) * 8;
    const unsigned short* Bg = Bt + (size_t)(tile_n * 128 + (tid >> 2)) * DIM + (tid & 3) * 8;

    unsigned short* AsW = As + wave * 512;    // wave-uniform LDS bases
    unsigned short* BsW = Bs + wave * 512;

    f32x4 acc[2][4] = {};

    for (int kk = 0; kk < DIM; kk += 32) {
        __syncthreads();
        gload_lds16(Ag + kk,            AsW);
        gload_lds16(Bg + kk,            BsW);
        gload_lds16(Bg + kk + 64 * DIM, BsW + 2048);
        __syncthreads();

        short8 af[2], bf[4];
#pragma unroll
        for (int i = 0; i < 2; ++i)
            af[i] = *(const short8*)(As + (wm * 32 + i * 16 + l15) * 32 + quad * 8);
#pragma unroll
        for (int j = 0; j < 4; ++j)
            bf[j] = *(const short8*)(Bs + (wn * 64 + j * 16 + l15) * 32 + quad * 8);
#pragma unroll
        for (int i = 0; i < 2; ++i)
#pragma unroll
            for (int j = 0; j < 4; ++j)
                acc[i][j] = __builtin_amdgcn_mfma_f32_16x16x32_bf16(af[i], bf[j], acc[i][j], 0, 0, 0);
    }

    // Epilogue. C/D layout: col = lane&15, row = quad*4 + reg.
    const int colg = tile_n * 128 + wn * 64 + l15;
    float bv[4];
#pragma unroll
    for (int j = 0; j < 4; ++j) bv[j] = bias[colg + j * 16];

#pragma unroll
    for (int i = 0; i < 2; ++i) {
#pragma unroll
        for (int r = 0; r < 4; ++r) {
            int lrow = wm * 32 + i * 16 + quad * 4 + r;
            int grow = rmap[lrow];
            if (grow >= 0) {
                float* orow = out + (size_t)grow * DIM + colg;
#pragma unroll
                for (int j = 0; j < 4; ++j)
                    orow[j * 16] = acc[i][j][r] + bv[j];
            }
        }
    }
}

extern "C" void kernel_launch(void* const* d_in, const int* in_sizes, int n_in,
                              void* d_out, int out_size, void* d_ws, size_t ws_size,
                              hipStream_t stream)
{
    const int*   token       = (const int*)d_in[0];
    const int*   need_mapper = (const int*)d_in[1];
    const float* emb         = (const float*)d_in[2];
    const float* w           = (const float*)d_in[3];
    const float* bias        = (const float*)d_in[4];
    float* out = (float*)d_out;

    const int ntok = in_sizes[0];   // 32*512 = 16384

    const size_t ACMP_B  = (size_t)ntok * DIM * 2;        // 25.2 MB (upper bound)
    const size_t BT_B    = (size_t)DIM * DIM * 2;         // 1.18 MB
    unsigned short* Acmp = (unsigned short*)d_ws;
    unsigned short* Bt   = (unsigned short*)((char*)d_ws + ACMP_B);
    int* rowmap          = (int*)((char*)d_ws + ACMP_B + BT_B);
    int* cnt             = (int*)((char*)d_ws + ACMP_B + BT_B + (size_t)ntok * 4);

    hipMemsetAsync(cnt, 0, 4, stream);

    const int nGatherBlk = ntok / 16;                     // 1024
    prep_kernel<<<dim3(nGatherBlk + 144), dim3(1024), 0, stream>>>(
        token, need_mapper, emb, w, out, Acmp, Bt, rowmap, cnt, nGatherBlk);
    gemm_kernel<<<dim3(DIM / 128, ntok / 64), dim3(256), 0, stream>>>(
        Acmp, Bt, bias, rowmap, cnt, out);
}

// Round 7
// 246.109 us; speedup vs baseline: 1.0130x; 1.0130x over previous
//
#include <hip/hip_runtime.h>
#include <hip/hip_bf16.h>
#include <stdint.h>
#include <stddef.h>

#define DIM 768

typedef short short8 __attribute__((ext_vector_type(8)));
typedef float f32x4 __attribute__((ext_vector_type(4)));

__device__ inline unsigned short f2bf_rne(float f) {
    union { float f; unsigned u; } x; x.f = f;
    unsigned r = x.u + 0x7fffu + ((x.u >> 16) & 1u);
    return (unsigned short)(r >> 16);
}

__device__ inline void gload_lds16(const void* g, void* l) {
    __builtin_amdgcn_global_load_lds((const __attribute__((address_space(1))) void*)g,
                                     (__attribute__((address_space(3))) void*)l, 16, 0, 0);
}

// Prep kernel, 1024 threads/block (R5 — proven).
//  Blocks [0, ntok/16): wave-per-row gather + block-aggregated compaction.
//  Blocks [ntok/16, +144): W [K][N] fp32 -> Bt [N][K] bf16 via LDS transpose.
__global__ __launch_bounds__(1024) void prep_kernel(
    const int* __restrict__ token,
    const int* __restrict__ need_mapper,
    const float* __restrict__ emb,
    const float* __restrict__ w,
    float* __restrict__ out,
    unsigned short* __restrict__ Acmp,
    unsigned short* __restrict__ Bt,
    int* __restrict__ rowmap,
    int* __restrict__ cnt,
    int nGatherBlk)
{
    const int tid = threadIdx.x;
    if ((int)blockIdx.x < nGatherBlk) {
        __shared__ int sneed[16], soffs[16], sbase;
        const int wave = tid >> 6, lane = tid & 63;
        const int r = blockIdx.x * 16 + wave;
        const int tok = token[r];
        const int need = need_mapper[tok];
        if (lane == 0) sneed[wave] = need;

        const float* src = emb + (size_t)tok * DIM;
        float4 v[3];
#pragma unroll
        for (int j = 0; j < 3; ++j)
            v[j] = *(const float4*)(src + (j * 64 + lane) * 4);

        __syncthreads();
        if (tid == 0) {
            int tot = 0;
#pragma unroll
            for (int i = 0; i < 16; ++i) { soffs[i] = tot; tot += sneed[i]; }
            sbase = atomicAdd(cnt, tot);
        }
        __syncthreads();

        if (need) {
            const int pos = sbase + soffs[wave];
            if (lane == 0) rowmap[pos] = r;
            unsigned short* arow = Acmp + (size_t)pos * DIM;
#pragma unroll
            for (int j = 0; j < 3; ++j) {
                ushort4 h;
                h.x = f2bf_rne(v[j].x); h.y = f2bf_rne(v[j].y);
                h.z = f2bf_rne(v[j].z); h.w = f2bf_rne(v[j].w);
                *(ushort4*)(arow + (j * 64 + lane) * 4) = h;
            }
        } else {
            float* drow = out + (size_t)r * DIM;
#pragma unroll
            for (int j = 0; j < 3; ++j)
                *(float4*)(drow + (j * 64 + lane) * 4) = v[j];
        }
        return;
    }

    __shared__ unsigned short t[64][65];
    const int b = blockIdx.x - nGatherBlk;        // 0..143
    const int k0 = (b / 12) * 64, n0 = (b % 12) * 64;
#pragma unroll
    for (int p = 0; p < 4; ++p) {
        int e = p * 1024 + tid;
        int r = e >> 6, c = e & 63;
        t[c][r] = f2bf_rne(w[(size_t)(k0 + r) * DIM + n0 + c]);
    }
    __syncthreads();
#pragma unroll
    for (int p = 0; p < 4; ++p) {
        int e = p * 1024 + tid;
        int r = e >> 6, c = e & 63;
        Bt[(size_t)(n0 + r) * DIM + k0 + c] = t[r][c];
    }
}

// GEMM on compacted rows, 128x128 tile, BK=32, PING-PONG DOUBLE-BUFFERED:
// one __syncthreads per K-step; prefetch for step k+1 issued right after the
// barrier, so the whole ds_read+MFMA phase of step k covers its latency
// (short-K / low-occupancy regime: this is where the m97 2-barrier pattern
// exposes the full load latency 24 times).
__global__ __launch_bounds__(256) void gemm_kernel(
    const unsigned short* __restrict__ A,    // [Mp][768] bf16, compacted
    const unsigned short* __restrict__ Bt,   // [768][768] bf16, n-major
    const float* __restrict__ bias,
    const int* __restrict__ rowmap,
    const int* __restrict__ cnt,
    float* __restrict__ out)
{
    const int Mp = *cnt;
    const int tile_n = blockIdx.x;
    const int tile_m = blockIdx.y;
    if (tile_m * 128 >= Mp) return;

    __shared__ unsigned short As[2][128 * 32];   // 2 x 8 KB
    __shared__ unsigned short Bs[2][128 * 32];   // 2 x 8 KB

    const int tid  = threadIdx.x;
    const int wave = tid >> 6;
    const int lane = tid & 63;
    const int quad = lane >> 4;
    const int l15  = lane & 15;
    const int wm   = wave >> 1;
    const int wn   = wave & 1;

    const int srow = tid >> 2;
    const int schk = (tid & 3) * 8;
    const unsigned short* Ag = A  + (size_t)(tile_m * 128 + srow) * DIM + schk;
    const unsigned short* Bg = Bt + (size_t)(tile_n * 128 + srow) * DIM + schk;

    const int woff = wave * 512;                 // wave-uniform LDS offset (ushorts)

    f32x4 acc[4][4] = {};

    // Prologue: stage K-step 0 into buffer 0.
    gload_lds16(Ag,            As[0] + woff);
    gload_lds16(Ag + 64 * DIM, As[0] + woff + 2048);
    gload_lds16(Bg,            Bs[0] + woff);
    gload_lds16(Bg + 64 * DIM, Bs[0] + woff + 2048);

#pragma unroll 1
    for (int it = 0; it < DIM / 32; ++it) {
        const int cur = it & 1;
        __syncthreads();   // drains step-it staging; protects buf(cur^1) reuse
        if (it + 1 < DIM / 32) {
            const int kk = (it + 1) * 32;
            unsigned short* An = As[cur ^ 1] + woff;
            unsigned short* Bn = Bs[cur ^ 1] + woff;
            gload_lds16(Ag + kk,            An);
            gload_lds16(Ag + kk + 64 * DIM, An + 2048);
            gload_lds16(Bg + kk,            Bn);
            gload_lds16(Bg + kk + 64 * DIM, Bn + 2048);
        }

        short8 af[4], bf[4];
#pragma unroll
        for (int i = 0; i < 4; ++i)
            af[i] = *(const short8*)(As[cur] + (wm * 64 + i * 16 + l15) * 32 + quad * 8);
#pragma unroll
        for (int j = 0; j < 4; ++j)
            bf[j] = *(const short8*)(Bs[cur] + (wn * 64 + j * 16 + l15) * 32 + quad * 8);
#pragma unroll
        for (int i = 0; i < 4; ++i)
#pragma unroll
            for (int j = 0; j < 4; ++j)
                acc[i][j] = __builtin_amdgcn_mfma_f32_16x16x32_bf16(af[i], bf[j], acc[i][j], 0, 0, 0);
    }

    // Epilogue. C/D layout: col = lane&15, row = quad*4 + reg.
    const int colg = tile_n * 128 + wn * 64 + l15;
    float bv[4];
#pragma unroll
    for (int j = 0; j < 4; ++j) bv[j] = bias[colg + j * 16];

    const int row0 = tile_m * 128 + wm * 64 + quad * 4;
#pragma unroll
    for (int i = 0; i < 4; ++i) {
#pragma unroll
        for (int r = 0; r < 4; ++r) {
            int gm = row0 + i * 16 + r;
            if (gm < Mp) {
                float* orow = out + (size_t)rowmap[gm] * DIM + colg;
#pragma unroll
                for (int j = 0; j < 4; ++j)
                    orow[j * 16] = acc[i][j][r] + bv[j];
            }
        }
    }
}

extern "C" void kernel_launch(void* const* d_in, const int* in_sizes, int n_in,
                              void* d_out, int out_size, void* d_ws, size_t ws_size,
                              hipStream_t stream)
{
    const int*   token       = (const int*)d_in[0];
    const int*   need_mapper = (const int*)d_in[1];
    const float* emb         = (const float*)d_in[2];
    const float* w           = (const float*)d_in[3];
    const float* bias        = (const float*)d_in[4];
    float* out = (float*)d_out;

    const int ntok = in_sizes[0];   // 32*512 = 16384

    const size_t ACMP_B  = (size_t)ntok * DIM * 2;        // 25.2 MB (upper bound)
    const size_t BT_B    = (size_t)DIM * DIM * 2;         // 1.18 MB
    unsigned short* Acmp = (unsigned short*)d_ws;
    unsigned short* Bt   = (unsigned short*)((char*)d_ws + ACMP_B);
    int* rowmap          = (int*)((char*)d_ws + ACMP_B + BT_B);
    int* cnt             = (int*)((char*)d_ws + ACMP_B + BT_B + (size_t)ntok * 4);

    hipMemsetAsync(cnt, 0, 4, stream);

    const int nGatherBlk = ntok / 16;                     // 1024
    prep_kernel<<<dim3(nGatherBlk + 144), dim3(1024), 0, stream>>>(
        token, need_mapper, emb, w, out, Acmp, Bt, rowmap, cnt, nGatherBlk);
    gemm_kernel<<<dim3(DIM / 128, ntok / 128), dim3(256), 0, stream>>>(
        Acmp, Bt, bias, rowmap, cnt, out);
}